// Round 6
// baseline (135.059 us; speedup 1.0000x reference)
//
#include <hip/hip_runtime.h>

// SparseAttention: B=4, M=4096, N=4096, D=128, W=128, fp32 in/out.
// Round 6: logits via MFMA 16x16x32_f16 with B-fragments gathered DIRECTLY from
// global K (fp16): one wave-load = 16 rows x 64 B, same line traffic as R4 but
// zero shuffles (R4/R5 were DS-pipe bound on the 4-deep shuffle chains).
// A-fragment = q broadcast (LDS stride-0). Sparse fp32 V phase kept from R4.

typedef __attribute__((ext_vector_type(8))) _Float16 half8;
typedef __attribute__((ext_vector_type(4))) float f32x4;

constexpr int Bc = 4, Mc = 4096, Nc = 4096, Dc = 128, Wc = 128;
constexpr size_t KV_ELEMS = (size_t)Bc * Nc * Dc;   // 2,097,152 per tensor
constexpr float EPS_P = 5e-5f;

// ---- fp32 -> fp16 conversion pre-pass (K only), 8 elems/thread ----
__global__ __launch_bounds__(256) void cvt_kernel(
    const float* __restrict__ k3d, _Float16* __restrict__ kh)
{
    const size_t i = ((size_t)blockIdx.x * blockDim.x + threadIdx.x) * 8;
    if (i >= KV_ELEMS) return;
    const float4 ka = *reinterpret_cast<const float4*>(k3d + i);
    const float4 kb = *reinterpret_cast<const float4*>(k3d + i + 4);
    half8 hk;
    hk[0]=(_Float16)ka.x; hk[1]=(_Float16)ka.y; hk[2]=(_Float16)ka.z; hk[3]=(_Float16)ka.w;
    hk[4]=(_Float16)kb.x; hk[5]=(_Float16)kb.y; hk[6]=(_Float16)kb.z; hk[7]=(_Float16)kb.w;
    *reinterpret_cast<half8*>(kh + i) = hk;
}

__global__ __launch_bounds__(128, 8) void sparse_attn_mfma(
    const float*    __restrict__ q3d,
    const _Float16* __restrict__ kh,
    const float*    __restrict__ v3d,
    const int*      __restrict__ cidx,
    float*          __restrict__ out)
{
    // XCD-aware decode: batch b pinned to XCD pair {2b,2b+1}.
    const int blk = blockIdx.x;
    const int xcd = blk & 7;
    const int b   = xcd >> 1;
    const int m   = ((blk >> 3) << 1) | (xcd & 1);
    const int t   = threadIdx.x;          // 0..127

    __shared__ __align__(16) _Float16 qsh[Dc];
    __shared__ int    cs[Wc];
    __shared__ float  ls[Wc];
    __shared__ float  wred[2];
    __shared__ float  wred2[2];
    __shared__ int    widx[Wc];           // compacted: row index * 32 (float4 units)
    __shared__ float  wp[Wc];             // compacted: weight
    __shared__ int    cnt;
    __shared__ float4 accs[4][32];

    qsh[t] = (_Float16)q3d[((size_t)b * Mc + m) * Dc + t];
    cs[t]  = cidx[m * Wc + t];
    if (t == 0) cnt = 0;
    __syncthreads();

    const int wave = t >> 6;    // 0..1 (wave handles tiles wave*4 .. wave*4+3)
    const int lane = t & 63;
    const int nl   = lane & 15; // n within tile (the w-row this lane gathers)
    const int gq   = lane >> 4; // quad 0..3 (k-subrange (gq*8..gq*8+7) within step)

    // A-fragments: A[m][k] = q[k] for ALL m (stride-0 broadcast read from LDS).
    // Every output row then holds the same logits; we read row 0.
    half8 afrag[4];
    #pragma unroll
    for (int s = 0; s < 4; ++s)
        afrag[s] = *reinterpret_cast<const half8*>(&qsh[s * 32 + gq * 8]);

    const half8* kb8 = reinterpret_cast<const half8*>(kh + (size_t)b * Nc * Dc);

    // ---- Phase 1: logits via MFMA; B-fragments gathered straight from global.
    // B[k=(gq*8+j)][n=nl] = K[cs[tile*16+nl]][s*32+gq*8+j]
    //   -> per lane one 16B load at row_base + s*64 + gq*16. 16 rows/instr.
    f32x4 acc[4];
    #pragma unroll
    for (int i = 0; i < 4; ++i) {
        const int tile = wave * 4 + i;
        const int ridx = cs[tile * 16 + nl] * 16;   // row offset in half8 units
        const half8 b0 = kb8[ridx + 0*4 + gq];
        const half8 b1 = kb8[ridx + 1*4 + gq];
        const half8 b2 = kb8[ridx + 2*4 + gq];
        const half8 b3 = kb8[ridx + 3*4 + gq];
        f32x4 a = {0.f, 0.f, 0.f, 0.f};
        a = __builtin_amdgcn_mfma_f32_16x16x32_f16(afrag[0], b0, a, 0, 0, 0);
        a = __builtin_amdgcn_mfma_f32_16x16x32_f16(afrag[1], b1, a, 0, 0, 0);
        a = __builtin_amdgcn_mfma_f32_16x16x32_f16(afrag[2], b2, a, 0, 0, 0);
        a = __builtin_amdgcn_mfma_f32_16x16x32_f16(afrag[3], b3, a, 0, 0, 0);
        acc[i] = a;
    }
    // C/D layout: col = lane&15, row = (lane>>4)*4 + reg. Row 0 => lanes 0-15, reg 0.
    if (lane < 16) {
        #pragma unroll
        for (int i = 0; i < 4; ++i)
            ls[(wave * 4 + i) * 16 + nl] = acc[i][0];
    }
    __syncthreads();

    // ---- Softmax over 128 logits (exact denominator over ALL rows) ----
    float L = ls[t];
    float mx = L;
    #pragma unroll
    for (int o = 32; o; o >>= 1) mx = fmaxf(mx, __shfl_xor(mx, o));
    if ((t & 63) == 0) wred[t >> 6] = mx;
    __syncthreads();
    mx = fmaxf(wred[0], wred[1]);
    const float e = __expf(L - mx);
    float s = e;
    #pragma unroll
    for (int o = 32; o; o >>= 1) s += __shfl_xor(s, o);
    if ((t & 63) == 0) wred2[t >> 6] = s;
    __syncthreads();
    s = wred2[0] + wred2[1];
    const float p = e / s;

    // ---- Compact the significant rows (typically ~6 of 128) ----
    if (p >= EPS_P) {
        const int slot = atomicAdd(&cnt, 1);
        widx[slot] = cs[t] * 32;          // float4-unit offset of the V row
        wp[slot]   = p;
    }
    __syncthreads();
    const int n = cnt;                    // >= 1 always (max p >= 1/128)

    // ---- Phase 2: sparse V gather, fp32 exact. Quarter-wave x float4 = one row.
    const int q32 = t >> 5;   // quarter 0..3
    const int l32 = t & 31;   // covers d = l32*4 .. l32*4+3
    const float4* vb = reinterpret_cast<const float4*>(v3d + (size_t)b * Nc * Dc);

    float4 acc2 = {0.f, 0.f, 0.f, 0.f};
    for (int e2 = q32; e2 < n; e2 += 4) {
        const float pw = wp[e2];
        const float4 v4 = vb[widx[e2] + l32];
        acc2.x += pw * v4.x;
        acc2.y += pw * v4.y;
        acc2.z += pw * v4.z;
        acc2.w += pw * v4.w;
    }
    accs[q32][l32] = acc2;
    __syncthreads();

    if (t < 32) {
        const float4 a0 = accs[0][t], a1 = accs[1][t], a2 = accs[2][t], a3 = accs[3][t];
        float4 o;
        o.x = a0.x + a1.x + a2.x + a3.x;
        o.y = a0.y + a1.y + a2.y + a3.y;
        o.z = a0.z + a1.z + a2.z + a3.z;
        o.w = a0.w + a1.w + a2.w + a3.w;
        reinterpret_cast<float4*>(out + ((size_t)b * Mc + m) * Dc)[t] = o;
    }
}

extern "C" void kernel_launch(void* const* d_in, const int* in_sizes, int n_in,
                              void* d_out, int out_size, void* d_ws, size_t ws_size,
                              hipStream_t stream) {
    const float* q = (const float*)d_in[0];
    const float* k = (const float*)d_in[1];
    const float* v = (const float*)d_in[2];
    const int*   c = (const int*)d_in[3];
    float*       o = (float*)d_out;
    (void)in_sizes; (void)n_in; (void)out_size; (void)ws_size;

    _Float16* kh = (_Float16*)d_ws;            // 4 MB

    const int cvt_threads = 256;
    const int cvt_blocks  = (int)(KV_ELEMS / 8 / cvt_threads);   // 1024
    cvt_kernel<<<cvt_blocks, cvt_threads, 0, stream>>>(k, kh);

    sparse_attn_mfma<<<dim3(Bc * Mc), dim3(128), 0, stream>>>(q, kh, v, c, o);
}

// Round 7
// 100.740 us; speedup vs baseline: 1.3407x; 1.3407x over previous
//
#include <hip/hip_runtime.h>

// SparseAttention: B=4, M=4096, N=4096, D=128, W=128, fp32 in/out.
// Round 7: R4 algorithm (fp16 K logits + sparse fp32 V), restructured for
// memory-level parallelism: all 16 K-chunk loads hoisted into registers
// (16 independent loads in flight per wave), consumption is fdot2 + a
// fire-and-forget LDS partial write (no dependent shuffle chains).
// Row reduction after the barrier via conflict-free ds_read_b32 sweeps.

typedef __attribute__((ext_vector_type(2))) _Float16 half2v;
typedef __attribute__((ext_vector_type(8))) _Float16 half8;

constexpr int Bc = 4, Mc = 4096, Nc = 4096, Dc = 128, Wc = 128;
constexpr size_t KV_ELEMS = (size_t)Bc * Nc * Dc;   // 2,097,152 per tensor
constexpr float EPS_P = 5e-5f;

// ---- fp32 -> fp16 conversion pre-pass (K only), 8 elems/thread ----
__global__ __launch_bounds__(256) void cvt_kernel(
    const float* __restrict__ k3d, _Float16* __restrict__ kh)
{
    const size_t i = ((size_t)blockIdx.x * blockDim.x + threadIdx.x) * 8;
    if (i >= KV_ELEMS) return;
    const float4 ka = *reinterpret_cast<const float4*>(k3d + i);
    const float4 kb = *reinterpret_cast<const float4*>(k3d + i + 4);
    half8 hk;
    hk[0]=(_Float16)ka.x; hk[1]=(_Float16)ka.y; hk[2]=(_Float16)ka.z; hk[3]=(_Float16)ka.w;
    hk[4]=(_Float16)kb.x; hk[5]=(_Float16)kb.y; hk[6]=(_Float16)kb.z; hk[7]=(_Float16)kb.w;
    *reinterpret_cast<half8*>(kh + i) = hk;
}

__global__ __launch_bounds__(128) void sparse_attn_mlp(
    const float*    __restrict__ q3d,
    const _Float16* __restrict__ kh,
    const float*    __restrict__ v3d,
    const int*      __restrict__ cidx,
    float*          __restrict__ out)
{
    // XCD-aware decode: batch b pinned to XCD pair {2b,2b+1}.
    const int blk = blockIdx.x;
    const int xcd = blk & 7;
    const int b   = xcd >> 1;
    const int m   = ((blk >> 3) << 1) | (xcd & 1);
    const int t   = threadIdx.x;          // 0..127

    __shared__ __align__(16) _Float16 qsh[Dc];
    __shared__ int    cs[Wc];
    // part[l][w]: partial dot of row w from d-chunk l. Stride 132 -> bank
    // (4l + w) % 32: 2-way aliasing on both write and read patterns = free.
    __shared__ float  part[16][Wc + 4];
    __shared__ float  wred[2];
    __shared__ float  wred2[2];
    __shared__ int    widx[Wc];           // compacted: row index * 32 (float4 units)
    __shared__ float  wp[Wc];             // compacted: weight
    __shared__ int    cnt;
    __shared__ float4 accs[4][32];

    qsh[t] = (_Float16)q3d[((size_t)b * Mc + m) * Dc + t];
    cs[t]  = cidx[m * Wc + t];
    if (t == 0) cnt = 0;
    __syncthreads();

    const int g = t >> 4;   // row-group 0..7: handles rows w = i*8+g
    const int l = t & 15;   // d-chunk lane: covers d = l*8 .. l*8+7

    const half8* kb8 = reinterpret_cast<const half8*>(kh + (size_t)b * Nc * Dc);

    const half8 qv = *reinterpret_cast<const half8*>(&qsh[l * 8]);
    const half2v q0 = {qv[0], qv[1]}, q1 = {qv[2], qv[3]},
                 q2 = {qv[4], qv[5]}, q3 = {qv[6], qv[7]};

    // ---- Phase 1a: issue ALL 16 gathers before any consumption ----
    int rb[16];
    #pragma unroll
    for (int i = 0; i < 16; ++i) rb[i] = cs[i * 8 + g] * 16;
    half8 kr[16];
    #pragma unroll
    for (int i = 0; i < 16; ++i) kr[i] = kb8[rb[i] + l];

    // ---- Phase 1b: consume -> LDS partials (fire-and-forget, no chains) ----
    #pragma unroll
    for (int i = 0; i < 16; ++i) {
        const half8 kv = kr[i];
        const half2v k0 = {kv[0], kv[1]}, k1 = {kv[2], kv[3]},
                     k2 = {kv[4], kv[5]}, k3 = {kv[6], kv[7]};
        float p = __builtin_amdgcn_fdot2(q0, k0, 0.f, false);
        p = __builtin_amdgcn_fdot2(q1, k1, p, false);
        p = __builtin_amdgcn_fdot2(q2, k2, p, false);
        p = __builtin_amdgcn_fdot2(q3, k3, p, false);
        part[l][i * 8 + g] = p;
    }
    __syncthreads();

    // ---- Row reduction: thread t sums the 16 partials of row t ----
    float L = 0.f;
    #pragma unroll
    for (int j = 0; j < 16; ++j) L += part[j][t];

    // ---- Softmax over 128 logits (exact denominator over ALL rows) ----
    float mx = L;
    #pragma unroll
    for (int o = 32; o; o >>= 1) mx = fmaxf(mx, __shfl_xor(mx, o));
    if ((t & 63) == 0) wred[t >> 6] = mx;
    __syncthreads();
    mx = fmaxf(wred[0], wred[1]);
    const float e = __expf(L - mx);
    float s = e;
    #pragma unroll
    for (int o = 32; o; o >>= 1) s += __shfl_xor(s, o);
    if ((t & 63) == 0) wred2[t >> 6] = s;
    __syncthreads();
    s = wred2[0] + wred2[1];
    const float p = e / s;

    // ---- Compact the significant rows (typically ~6 of 128) ----
    if (p >= EPS_P) {
        const int slot = atomicAdd(&cnt, 1);
        widx[slot] = cs[t] * 32;          // float4-unit offset of the V row
        wp[slot]   = p;
    }
    __syncthreads();
    const int n = cnt;                    // >= 1 always (max p >= 1/128)

    // ---- Phase 2: sparse V gather, fp32 exact. Quarter-wave x float4 = one row.
    const int q32 = t >> 5;   // quarter 0..3
    const int l32 = t & 31;   // covers d = l32*4 .. l32*4+3
    const float4* vb = reinterpret_cast<const float4*>(v3d + (size_t)b * Nc * Dc);

    float4 acc2 = {0.f, 0.f, 0.f, 0.f};
    for (int e2 = q32; e2 < n; e2 += 4) {
        const float pw = wp[e2];
        const float4 v4 = vb[widx[e2] + l32];
        acc2.x += pw * v4.x;
        acc2.y += pw * v4.y;
        acc2.z += pw * v4.z;
        acc2.w += pw * v4.w;
    }
    accs[q32][l32] = acc2;
    __syncthreads();

    if (t < 32) {
        const float4 a0 = accs[0][t], a1 = accs[1][t], a2 = accs[2][t], a3 = accs[3][t];
        float4 o;
        o.x = a0.x + a1.x + a2.x + a3.x;
        o.y = a0.y + a1.y + a2.y + a3.y;
        o.z = a0.z + a1.z + a2.z + a3.z;
        o.w = a0.w + a1.w + a2.w + a3.w;
        reinterpret_cast<float4*>(out + ((size_t)b * Mc + m) * Dc)[t] = o;
    }
}

extern "C" void kernel_launch(void* const* d_in, const int* in_sizes, int n_in,
                              void* d_out, int out_size, void* d_ws, size_t ws_size,
                              hipStream_t stream) {
    const float* q = (const float*)d_in[0];
    const float* k = (const float*)d_in[1];
    const float* v = (const float*)d_in[2];
    const int*   c = (const int*)d_in[3];
    float*       o = (float*)d_out;
    (void)in_sizes; (void)n_in; (void)out_size; (void)ws_size;

    _Float16* kh = (_Float16*)d_ws;            // 4 MB

    const int cvt_threads = 256;
    const int cvt_blocks  = (int)(KV_ELEMS / 8 / cvt_threads);   // 1024
    cvt_kernel<<<cvt_blocks, cvt_threads, 0, stream>>>(k, kh);

    sparse_attn_mlp<<<dim3(Bc * Mc), dim3(128), 0, stream>>>(q, kh, v, c, o);
}